// Round 14
// baseline (285.069 us; speedup 1.0000x reference)
//
#include <hip/hip_runtime.h>
#include <hip/hip_fp16.h>
#include <cstdint>
#include <cstddef>

using u16 = unsigned short;
using u32 = unsigned int;

typedef _Float16 half8 __attribute__((ext_vector_type(8)));
typedef float f32x4 __attribute__((ext_vector_type(4)));

#define MF(a, b, c) __builtin_amdgcn_mfma_f32_16x16x32_f16((a), (b), (c), 0, 0, 0)

static inline int cdiv(int a, int b) { return (a + b - 1) / b; }

// ===========================================================================
// prep_k: zero-init + HOT-slice panels only + rule precompute.
// wsp = [l][40 panels][256 cols][8] covering K'=0..319 of the concat GEMM's
// tail (W_self K'<256, b_rule K'<272, zero-pad above). W_rule is NOT
// panelized — the (never-taken on this data) cold path inline-converts it
// from f32 during staging (r8-verified identical rounding). Saves ~40MB of
// prep traffic and ~12K prep blocks vs r12.
// ===========================================================================

__global__ void prep_k(const float* __restrict__ Ws, const float* __restrict__ br,
                       const float* __restrict__ W_in, const float* __restrict__ W_h1,
                       const float* __restrict__ W_h2,
                       const float* __restrict__ centers, const float* __restrict__ logsig,
                       u16* __restrict__ wsp,
                       u16* __restrict__ winp, u16* __restrict__ wh1p,
                       u16* __restrict__ wh2p,
                       u16* __restrict__ pcB, float* __restrict__ pccc,
                       int* __restrict__ zerobase, int nzero,
                       int Z, int Wb) {
    const int bid = blockIdx.x;
    const int tid = threadIdx.x;
    if (bid < Z) {                                   // zero-init region
        int i = bid * 256 + tid;
        if (i < nzero) zerobase[i] = 0;
        return;
    }
    if (bid < Z + Wb) {                              // wsp panels [40][256][8] x3 layers
        size_t t = (size_t)(bid - Z) * 256 + tid;
        const size_t PL = 40u * 256u * 8u;           // 81920 per layer
        int l = (int)(t / PL);
        size_t rem = t - (size_t)l * PL;
        int kp = (int)(rem >> 11);
        int o = (int)((rem >> 3) & 255);
        int e = (int)(rem & 7);
        int kk = kp * 8 + e;                         // K' in [0,320)
        float v;
        if (kk < 256)      v = Ws[(((size_t)l * 256) + kk) * 256 + o];
        else if (kk < 272) v = br[(((size_t)l * 16) + (kk - 256)) * 256 + o];
        else               v = 0.f;
        union { u16 u; _Float16 h; } c; c.h = (_Float16)v;
        wsp[t] = c.u;
        return;
    }
    if (bid < Z + Wb + 128) {                        // panelize W_in (K=128,M=256)
        size_t t = (size_t)(bid - Z - Wb) * 256 + tid;
        int e = (int)(t & 7), o = (int)((t >> 3) & 255);
        int kp = (int)(t >> 11);
        union { u16 u; _Float16 h; } c; c.h = (_Float16)W_in[(size_t)(kp * 8 + e) * 256 + o];
        winp[t] = c.u;
        return;
    }
    if (bid < Z + Wb + 256) {                        // panelize W_h1 (K=256,M=128)
        size_t t = (size_t)(bid - Z - Wb - 128) * 256 + tid;
        int e = (int)(t & 7), o = (int)((t >> 3) & 127);
        int kp = (int)(t >> 10);
        union { u16 u; _Float16 h; } c; c.h = (_Float16)W_h1[(size_t)(kp * 8 + e) * 128 + o];
        wh1p[t] = c.u;
        return;
    }
    if (bid < Z + Wb + 256 + 24) {                   // panelize W_h2 (K=128,M=40->48 pad)
        int t = (bid - Z - Wb - 256) * 256 + tid;    // 16*48*8 = 6144
        int e = t & 7, col = (t >> 3) % 48, p = t / 384;
        int k = p * 8 + e;
        float v = (col < 40) ? W_h2[(size_t)k * 40 + col] : 0.f;
        union { u16 u; _Float16 h; } c; c.h = (_Float16)v;
        wh2p[t] = c.u;
        return;
    }
    {                                                // pc_build: 48 blocks (l*16+r)
        int lr = bid - (Z + Wb + 256 + 24);
        size_t idx = (size_t)lr * 256 + tid;
        float ls = logsig[idx];
        float inv = expf(-2.f * ls);
        float c = centers[idx];
        union { u16 u; _Float16 h; } c1, c2;
        c1.h = (_Float16)inv;
        c2.h = (_Float16)(-2.f * c * inv);
        pcB[(size_t)lr * 512 + tid] = c1.u;          // B[k][r] = inv_s2[r][k], k<256
        pcB[(size_t)lr * 512 + 256 + tid] = c2.u;    // B[256+k][r] = -2 c inv
        __shared__ float sm[256];
        sm[tid] = c * c * inv;
        __syncthreads();
        for (int s = 128; s > 0; s >>= 1) { if (tid < s) sm[tid] += sm[tid + s]; __syncthreads(); }
        if (tid == 0) pccc[lr] = sm[0];
    }
}

// ===========================================================================
// gemm_mn: full-width 128x256 LDS-staged GEMM (r12 structure, 271.6us best).
// MODE 0: h16 = relu(x@winp+b_in); fused membership from the LDS out-tile.
// MODE 1: cold-gated CSR prologue; pre16 = [mu*agg|h|mu]@[Wr|Ws|br] + b_self;
//   BN sums -> 8-way shadow atomics (r12-verified, -6us/dispatch).
//   B staging: hot chunks (cb>=64) read wsp panels; cold chunks (cb<64,
//   never taken on this data) inline-convert W_rule f32 (r8-verified).
// ===========================================================================

template <int MODE, int NCHUNK>
__launch_bounds__(256, 2)
__global__ void gemm_mn(const u16* __restrict__ A, const u16* __restrict__ A2,
                        const u16* __restrict__ MU, const u16* __restrict__ Bp,
                        const float* __restrict__ Wrf, int layer,
                        const float* __restrict__ bias, const int* __restrict__ bflag,
                        u16* __restrict__ outH, float* __restrict__ bnsum,
                        const u16* __restrict__ pcB, const float* __restrict__ pccc,
                        u16* __restrict__ mu16, int* __restrict__ bflagN,
                        const int* __restrict__ esrc, const int* __restrict__ edst,
                        int* __restrict__ deg, int* __restrict__ indptr,
                        int* __restrict__ cursor, float* __restrict__ deginv,
                        int* __restrict__ ssrc, int* __restrict__ csrctr,
                        int* __restrict__ done, int E, int nrows) {
    __shared__ __align__(16) u16 lds[24576];   // lA 8192 | lB 16384; out tile reuses [0..17407]
    __shared__ float bnbuf[2048];              // [wave][256 cols][s,ss]
    __shared__ int ssm[256];                   // cold-path scan
    u16* lA = lds;
    u16* lB = lds + 8192;
    const int tid = threadIdx.x;
    const int row0 = blockIdx.x * 128;
    const int lane = tid & 63;
    const int q = lane >> 4, mm = lane & 15;
    const int wave = tid >> 6;
    int nr = nrows - row0; if (nr > 128) nr = 128;

    // ---- cold-gated CSR build + own-row aggregation (MODE 1 only; r10-verified) ----
    if (MODE == 1 && bflag[511] != 0) {
        int bseq = 0;
        auto gbar = [&]() {
            __threadfence();
            __syncthreads();
            ++bseq;
            if (tid == 0) {
                atomicAdd(csrctr, 1);
                while (atomicAdd(csrctr, 0) < (int)gridDim.x * bseq)
                    __builtin_amdgcn_s_sleep(2);
            }
            __syncthreads();
        };
        if (*done == 0) {
            for (int e = blockIdx.x * 256 + tid; e < E; e += (int)gridDim.x * 256)
                atomicAdd(&deg[edst[e]], 1);
            gbar();
            if (blockIdx.x == 0) {                   // 256-thread scan
                const int n = nrows;
                const int chunk = (n + 255) >> 8;
                int s0 = tid * chunk, s1 = s0 + chunk;
                if (s1 > n) s1 = n; if (s0 > n) s0 = n;
                int tot = 0;
                for (int i = s0; i < s1; ++i) tot += atomicAdd(&deg[i], 0);
                ssm[tid] = tot; __syncthreads();
                for (int off = 1; off < 256; off <<= 1) {
                    int t = (tid >= off) ? ssm[tid - off] : 0;
                    __syncthreads(); ssm[tid] += t; __syncthreads();
                }
                int base = ssm[tid] - tot;
                for (int i = s0; i < s1; ++i) {
                    int d = atomicAdd(&deg[i], 0);
                    indptr[i] = base; cursor[i] = base;
                    deginv[i] = 1.f / (float)(d > 1 ? d : 1);
                    base += d;
                }
                if (tid == 255) indptr[nrows] = ssm[255];
            }
            gbar();
            for (int e = blockIdx.x * 256 + tid; e < E; e += (int)gridDim.x * 256) {
                int d = edst[e];
                int pos = atomicAdd(&cursor[d], 1);
                ssrc[pos] = esrc[e];
            }
            gbar();
            if (blockIdx.x == 0 && tid == 0) *done = 1;
        }
        if (bflag[blockIdx.x] != 0) {                // aggregate OWN 128 rows
            for (int node = row0 + wave; node < row0 + 128 && node < nrows; node += 4) {
                int j0 = indptr[node], j1 = indptr[node + 1];
                float a0 = 0, a1 = 0, a2 = 0, a3 = 0;
                for (int j = j0; j < j1; ++j) {
                    int sN = ssrc[j];
                    union { uint2 u; _Float16 h[4]; } hv;
                    hv.u = *(const uint2*)(A2 + (size_t)sN * 256 + lane * 4);
                    a0 += (float)hv.h[0]; a1 += (float)hv.h[1];
                    a2 += (float)hv.h[2]; a3 += (float)hv.h[3];
                }
                float di = deginv[node];
                union { uint2 u; _Float16 h[4]; } o;
                o.h[0] = (_Float16)(a0 * di); o.h[1] = (_Float16)(a1 * di);
                o.h[2] = (_Float16)(a2 * di); o.h[3] = (_Float16)(a3 * di);
                *(uint2*)((u16*)A + (size_t)node * 256 + lane * 4) = o.u;
            }
        }
        __threadfence_block();
        __syncthreads();
    }

    f32x4 acc[2][16];
#pragma unroll
    for (int i = 0; i < 2; ++i)
#pragma unroll
        for (int j = 0; j < 16; ++j) acc[i][j] = (f32x4){0.f, 0.f, 0.f, 0.f};

    int cb = 0, cbEnd = NCHUNK;
    if (MODE == 1 && bflag[blockIdx.x] == 0) { cb = 64; cbEnd = 68; }  // mu==0: fuzzy+mu K exact-zero

    for (; cb < cbEnd; ++cb) {
        // B chunk: 8 k-panels x 256 cols  (2048 uint4)
#pragma unroll
        for (int it = 0; it < 8; ++it) {
            int idx = it * 256 + tid;
            int p = idx >> 8, col = idx & 255;
            uint4 v;
            if (MODE == 0) {
                v = *(const uint4*)(Bp + (((size_t)(cb * 8 + p)) * 256 + col) * 8);
            } else if (cb >= 64) {                   // hot slice from wsp panels
                v = *(const uint4*)(Bp + (((size_t)((cb - 64) * 8 + p)) * 256 + col) * 8);
            } else {                                 // cold: inline f32 W_rule (r8-verified)
                int kb = cb * 64 + (p << 3);
                union { uint4 u4; _Float16 h[8]; } cv;
#pragma unroll
                for (int e = 0; e < 8; ++e) {
                    int k = kb + e;
                    cv.h[e] = (_Float16)Wrf[((((size_t)layer * 16 + (k >> 8)) * 256)
                                             + (k & 255)) * 256 + col];
                }
                v = cv.u4;
            }
            *(uint4*)(lB + (size_t)idx * 8) = v;
        }
        // A chunk: 128 rows x 64 k  (1024 uint4)
#pragma unroll
        for (int it = 0; it < 4; ++it) {
            int idx = it * 256 + tid;
            int p = idx >> 7, row = idx & 127;
            int grow = row0 + row; if (grow >= nrows) grow = nrows - 1;
            uint4 v;
            if (MODE == 0) {
                const float* xr = (const float*)A + (size_t)grow * 128 + cb * 64 + (p << 3);
                float4 f0 = *(const float4*)xr;
                float4 f1 = *(const float4*)(xr + 4);
                union { uint4 u4; _Float16 h[8]; } cv;
                cv.h[0] = (_Float16)f0.x; cv.h[1] = (_Float16)f0.y;
                cv.h[2] = (_Float16)f0.z; cv.h[3] = (_Float16)f0.w;
                cv.h[4] = (_Float16)f1.x; cv.h[5] = (_Float16)f1.y;
                cv.h[6] = (_Float16)f1.z; cv.h[7] = (_Float16)f1.w;
                v = cv.u4;
            } else {
                if (cb < 64) {
                    int r = cb >> 2;
                    int i0 = ((cb & 3) << 6) + (p << 3);
                    v = *(const uint4*)(A + (size_t)grow * 256 + i0);
                    union { u16 u; _Float16 h; } mu; mu.u = MU[(size_t)grow * 16 + r];
                    union { uint4 u4; _Float16 h[8]; } wv; wv.u4 = v;
#pragma unroll
                    for (int j = 0; j < 8; ++j) wv.h[j] = wv.h[j] * mu.h;
                    v = wv.u4;
                } else if (cb < 68) {
                    int i0 = ((cb - 64) << 6) + (p << 3);
                    v = *(const uint4*)(A2 + (size_t)grow * 256 + i0);
                } else {
                    int j0 = p << 3;
                    if (j0 < 16) v = *(const uint4*)(MU + (size_t)grow * 16 + j0);
                    else v = (uint4){0, 0, 0, 0};
                }
            }
            *(uint4*)(lA + (size_t)idx * 8) = v;
        }
        __syncthreads();
#pragma unroll
        for (int kc = 0; kc < 2; ++kc) {
            int pp = kc * 4 + q;
            half8 af0 = *(const half8*)(lA + ((size_t)pp * 128 + wave * 32 + mm) * 8);
            half8 af1 = *(const half8*)(lA + ((size_t)pp * 128 + wave * 32 + 16 + mm) * 8);
#pragma unroll
            for (int nt = 0; nt < 16; ++nt) {
                half8 bf = *(const half8*)(lB + ((size_t)pp * 256 + nt * 16 + mm) * 8);
                acc[0][nt] = MF(af0, bf, acc[0][nt]);
                acc[1][nt] = MF(af1, bf, acc[1][nt]);
            }
        }
        __syncthreads();
    }

    // ---- BN column sums (MODE 1): 8-way shadow atomics (r12-verified) ----
    if (MODE == 1) {
#pragma unroll
        for (int nt = 0; nt < 16; ++nt) {
            int cl = nt * 16 + mm;
            float bb = bias[cl];
            float s = 0.f, ss = 0.f;
#pragma unroll
            for (int mt = 0; mt < 2; ++mt) {
#pragma unroll
                for (int r = 0; r < 4; ++r) {
                    int row = wave * 32 + mt * 16 + q * 4 + r;
                    float v = acc[mt][nt][r] + bb;
                    if (row < nr) { s += v; ss += v * v; }
                }
            }
            s += __shfl_xor(s, 16);  s += __shfl_xor(s, 32);
            ss += __shfl_xor(ss, 16); ss += __shfl_xor(ss, 32);
            if (q == 0) {
                bnbuf[(wave * 256 + cl) * 2 + 0] = s;
                bnbuf[(wave * 256 + cl) * 2 + 1] = ss;
            }
        }
        __syncthreads();
        {
            float s  = bnbuf[tid * 2]     + bnbuf[(256 + tid) * 2]
                     + bnbuf[(512 + tid) * 2] + bnbuf[(768 + tid) * 2];
            float ss = bnbuf[tid * 2 + 1] + bnbuf[(256 + tid) * 2 + 1]
                     + bnbuf[(512 + tid) * 2 + 1] + bnbuf[(768 + tid) * 2 + 1];
            float* bnl = bnsum + (blockIdx.x & 7) * 512;   // 8 shadow copies
            atomicAdd(&bnl[tid], s);
            atomicAdd(&bnl[256 + tid], ss);
        }
    }

    // ---- store halves through LDS; MODE 0 fuses membership from the tile ----
    f32x4 macc0 = (f32x4){0.f, 0.f, 0.f, 0.f};
    f32x4 macc1 = (f32x4){0.f, 0.f, 0.f, 0.f};
#pragma unroll
    for (int h = 0; h < 2; ++h) {
        __syncthreads();
#pragma unroll
        for (int nt = 0; nt < 8; ++nt) {
            int cl = h * 128 + nt * 16 + mm;
            float bb = bias[cl];
#pragma unroll
            for (int mt = 0; mt < 2; ++mt) {
#pragma unroll
                for (int r = 0; r < 4; ++r) {
                    int row = wave * 32 + mt * 16 + q * 4 + r;
                    float v = acc[mt][h * 8 + nt][r] + bb;
                    if (MODE == 0) v = fmaxf(v, 0.f);
                    union { u16 u; _Float16 hh; } cc; cc.hh = (_Float16)v;
                    lds[row * 136 + nt * 16 + mm] = cc.u;
                }
            }
        }
        __syncthreads();
#pragma unroll
        for (int it = 0; it < 8; ++it) {
            int idx = it * 256 + tid;
            int row = idx >> 4, cp = idx & 15;
            if (row < nr) {
                uint4 v = *(const uint4*)(lds + row * 136 + cp * 8);
                *(uint4*)(outH + (size_t)(row0 + row) * 256 + h * 128 + cp * 8) = v;
            }
        }
        if (MODE == 0) {
            // membership partial MFMA over this half's 128 h-dims (reads tile)
            const u16* brow = pcB + (size_t)mm * 512;
#pragma unroll
            for (int it2 = 0; it2 < 4; ++it2) {
                int lk = it2 * 32 + q * 8;
                half8 b1 = *(const half8*)(brow + h * 128 + lk);
                half8 b2 = *(const half8*)(brow + 256 + h * 128 + lk);
                half8 a0 = *(const half8*)(lds + ((size_t)(wave * 32 + mm)) * 136 + lk);
                half8 a1 = *(const half8*)(lds + ((size_t)(wave * 32 + 16 + mm)) * 136 + lk);
                macc0 = MF(a0 * a0, b1, macc0);
                macc0 = MF(a0, b2, macc0);
                macc1 = MF(a1 * a1, b1, macc1);
                macc1 = MF(a1, b2, macc1);
            }
        }
    }

    if (MODE == 0) {
        float cc = pccc[mm];
        bool any = false;
#pragma unroll
        for (int g = 0; g < 2; ++g) {
            f32x4 macc = g ? macc1 : macc0;
#pragma unroll
            for (int r = 0; r < 4; ++r) {
                float d = macc[r] + cc;
                float f = expf(-0.5f * d);
                float s = f;
                s += __shfl_xor(s, 1); s += __shfl_xor(s, 2);
                s += __shfl_xor(s, 4); s += __shfl_xor(s, 8);
                int node = row0 + (wave * 2 + g) * 16 + q * 4 + r;
                if (node < nrows) {
                    union { u16 u; _Float16 hh; } c2;
                    c2.hh = (_Float16)(f / (s + 1e-12f));
                    mu16[(size_t)node * 16 + mm] = c2.u;
                    if (c2.u != 0) any = true;       // f16-visible firing only
                }
            }
        }
        if (__any(any) && lane == 0) {
            atomicOr(&bflagN[blockIdx.x], 1);
            atomicOr(&bflagN[511], 1);
        }
    }
}

// ===========================================================================
// upd_k: BN alpha/shift from 8-shadow bnsum (summed in-block), residual
// update. (r12) TAIL 1: h16 write + next-layer membership. TAIL 2: fused head.
// ===========================================================================

template <int TAIL>
__launch_bounds__(256)
__global__ void upd_k(const u16* __restrict__ pre16, const float* __restrict__ bnsum,
                      const float* __restrict__ gamma, const float* __restrict__ beta,
                      u16* __restrict__ h16,
                      const u16* __restrict__ pcB, const float* __restrict__ pccc,
                      u16* __restrict__ mu16, int* __restrict__ bflag,
                      const u16* __restrict__ wh1p, const float* __restrict__ bh1,
                      const u16* __restrict__ wh2p, const float* __restrict__ bh2,
                      float* __restrict__ outF, int n) {
    const int tid = threadIdx.x;
    __shared__ float l_ab[512];
    __shared__ __align__(16) u16 qt[4][2176];        // TAIL2: per-wave [16][136]
    {
        float su = 0.f, sq = 0.f;
#pragma unroll
        for (int c = 0; c < 8; ++c) {                // sum the 8 shadow copies
            su += bnsum[c * 512 + tid];
            sq += bnsum[c * 512 + 256 + tid];
        }
        float invn = 1.f / (float)n;
        float m = su * invn;
        float al = gamma[tid] * rsqrtf(sq * invn - m * m + 1e-5f);
        l_ab[tid] = al;
        l_ab[256 + tid] = beta[tid] - m * al;
    }
    __syncthreads();

    const int lane = tid & 63, wave = tid >> 6;
    const int q = lane >> 4, mm = lane & 15;
    const int n0 = (blockIdx.x * 4 + wave) * 16;
    if (n0 >= n) return;
    const int node = n0 + mm;
    const bool valid = node < n;
    const int nodeC = valid ? node : n - 1;
    const size_t base = (size_t)nodeC * 256 + q * 8;

    half8 v16[8];
#pragma unroll
    for (int b = 0; b < 8; ++b) {
        int c = b * 32 + q * 8;
        float4 alA = *(const float4*)(l_ab + c);
        float4 alB = *(const float4*)(l_ab + c + 4);
        float4 shA = *(const float4*)(l_ab + 256 + c);
        float4 shB = *(const float4*)(l_ab + 256 + c + 4);
        float aarr[8] = {alA.x, alA.y, alA.z, alA.w, alB.x, alB.y, alB.z, alB.w};
        float harr[8] = {shA.x, shA.y, shA.z, shA.w, shB.x, shB.y, shB.z, shB.w};
        union { uint4 u; _Float16 hh[8]; } p, hv, o;
        p.u  = *(const uint4*)(pre16 + base + b * 32);
        hv.u = *(const uint4*)(h16 + base + b * 32);
#pragma unroll
        for (int j = 0; j < 8; ++j) {
            float v = (float)hv.hh[j] + fmaxf((float)p.hh[j] * aarr[j] + harr[j], 0.f);
            o.hh[j] = (_Float16)v;
        }
        if (TAIL == 1 && valid) *(uint4*)(h16 + base + b * 32) = o.u;
        v16[b] = *(half8*)&o;
    }

    if (TAIL == 1) {
        const u16* brow = pcB + (size_t)mm * 512;
        f32x4 acc = (f32x4){0.f, 0.f, 0.f, 0.f};
#pragma unroll
        for (int it = 0; it < 16; ++it) {
            half8 a = v16[it & 7];
            if (it < 8) a = a * a;
            half8 bb = *(const half8*)(brow + it * 32 + q * 8);
            acc = MF(a, bb, acc);
        }
        float cc = pccc[mm];
        bool any = false;
#pragma unroll
        for (int r = 0; r < 4; ++r) {
            float d = acc[r] + cc;
            float f = expf(-0.5f * d);
            float s = f;
            s += __shfl_xor(s, 1); s += __shfl_xor(s, 2);
            s += __shfl_xor(s, 4); s += __shfl_xor(s, 8);
            int nd = n0 + q * 4 + r;
            if (nd < n) {
                union { u16 u; _Float16 h; } c2;
                c2.h = (_Float16)(f / (s + 1e-12f));
                mu16[(size_t)nd * 16 + mm] = c2.u;
                if (c2.u != 0) any = true;           // f16-visible firing only
            }
        }
        if (__any(any) && lane == 0) {
            atomicOr(&bflag[n0 >> 7], 1);
            atomicOr(&bflag[511], 1);
        }
    }

    if (TAIL == 2) {
        u16* qw = qt[wave];
        f32x4 hq[8];
#pragma unroll
        for (int j = 0; j < 8; ++j) hq[j] = (f32x4){0.f, 0.f, 0.f, 0.f};
#pragma unroll
        for (int b = 0; b < 8; ++b) {
            half8 a = v16[b];
            const u16* bp = wh1p + ((size_t)((b * 4 + q) * 128) + mm) * 8;
#pragma unroll
            for (int nt = 0; nt < 8; ++nt) {
                half8 bf = *(const half8*)(bp + nt * 128);
                hq[nt] = MF(a, bf, hq[nt]);
            }
        }
#pragma unroll
        for (int nt = 0; nt < 8; ++nt) {
            int cl = nt * 16 + mm;
            float bb = bh1[cl];
#pragma unroll
            for (int r = 0; r < 4; ++r) {
                float v = fmaxf(hq[nt][r] + bb, 0.f);
                union { u16 u; _Float16 h; } cc; cc.h = (_Float16)v;
                qw[(q * 4 + r) * 136 + cl] = cc.u;
            }
        }
        const bool c2ok = (mm < 8);
        float b0 = bh2[mm], b1 = bh2[16 + mm];
        float b2 = c2ok ? bh2[32 + mm] : 0.f;
        f32x4 hacc[3];
#pragma unroll
        for (int t = 0; t < 3; ++t) hacc[t] = (f32x4){0.f, 0.f, 0.f, 0.f};
#pragma unroll
        for (int c = 0; c < 4; ++c) {
            half8 a = *(const half8*)(qw + (size_t)mm * 136 + c * 32 + q * 8);
#pragma unroll
            for (int t = 0; t < 3; ++t) {
                half8 b = *(const half8*)(wh2p + ((size_t)(c * 4 + q) * 48 + t * 16 + mm) * 8);
                hacc[t] = MF(a, b, hacc[t]);
            }
        }
#pragma unroll
        for (int r = 0; r < 4; ++r) {
            int nd = n0 + q * 4 + r;
            float v0 = hacc[0][r] + b0;
            float v1 = hacc[1][r] + b1;
            float v2 = c2ok ? (hacc[2][r] + b2) : -3e38f;
            float m = fmaxf(fmaxf(v0, v1), v2);
            m = fmaxf(m, __shfl_xor(m, 1)); m = fmaxf(m, __shfl_xor(m, 2));
            m = fmaxf(m, __shfl_xor(m, 4)); m = fmaxf(m, __shfl_xor(m, 8));
            float e0 = expf(v0 - m), e1 = expf(v1 - m);
            float e2 = c2ok ? expf(v2 - m) : 0.f;
            float s = e0 + e1 + e2;
            s += __shfl_xor(s, 1); s += __shfl_xor(s, 2);
            s += __shfl_xor(s, 4); s += __shfl_xor(s, 8);
            float is = 1.f / s;
            if (nd < n) {
                float* op = outF + (size_t)nd * 40;
                op[mm] = e0 * is;
                op[16 + mm] = e1 * is;
                if (c2ok) op[32 + mm] = e2 * is;
            }
        }
    }
}

// ===========================================================================
// Launch: 8 dispatches (prep, g0, 3x(g1, upd)).
// ===========================================================================

extern "C" void kernel_launch(void* const* d_in, const int* in_sizes, int n_in,
                              void* d_out, int out_size, void* d_ws, size_t ws_size,
                              hipStream_t stream) {
    const float* x       = (const float*)d_in[0];
    const int*   ei      = (const int*)d_in[1];
    const float* W_in    = (const float*)d_in[2];
    const float* b_in    = (const float*)d_in[3];
    const float* centers = (const float*)d_in[4];
    const float* logsig  = (const float*)d_in[5];
    const float* W_rule  = (const float*)d_in[6];
    const float* b_rule  = (const float*)d_in[7];
    const float* W_self  = (const float*)d_in[8];
    const float* b_self  = (const float*)d_in[9];
    const float* gamma   = (const float*)d_in[10];
    const float* beta    = (const float*)d_in[11];
    const float* W_h1    = (const float*)d_in[12];
    const float* b_h1    = (const float*)d_in[13];
    const float* W_h2    = (const float*)d_in[14];
    const float* b_h2    = (const float*)d_in[15];

    const int N = in_sizes[0] / 128;
    const int E = in_sizes[1] / 2;
    const int* e_src = ei;
    const int* e_dst = ei + E;

    char* w = (char*)d_ws;
    size_t off = 0;
    auto alloc = [&](size_t bytes) -> void* {
        void* p = w + off;
        off = (off + bytes + 255) & ~(size_t)255;
        return p;
    };

    const int gx = cdiv(N, 128);

    u16*   h16    = (u16*)  alloc((size_t)N * 256 * 2);
    u16*   pre16  = (u16*)  alloc((size_t)N * 256 * 2);
    u16*   agg16  = (u16*)  alloc((size_t)N * 256 * 2);
    u16*   mu16   = (u16*)  alloc((size_t)N * 16 * 2);
    u16*   wsp    = (u16*)  alloc((size_t)3 * 40 * 256 * 8 * 2);
    u16*   winp   = (u16*)  alloc((size_t)16 * 256 * 8 * 2);
    u16*   wh1p   = (u16*)  alloc((size_t)32 * 128 * 8 * 2);
    u16*   wh2p   = (u16*)  alloc((size_t)16 * 48 * 8 * 2);
    u16*   pcB    = (u16*)  alloc((size_t)48 * 512 * 2);
    float* pccc   = (float*)alloc((size_t)48 * 4);
    int*   indptr = (int*)  alloc((size_t)(N + 1) * 4);
    int*   cursor = (int*)  alloc((size_t)N * 4);
    float* deginv = (float*)alloc((size_t)N * 4);
    int*   ssrc   = (int*)  alloc((size_t)E * 4);
    // zero region: [deg N][bflag 3*512][bnsum8 3*8*512][done, csrctr, pad]
    const int nzero = N + 3 * 512 + 3 * 8 * 512 + 16;
    int*   zerob  = (int*)  alloc((size_t)nzero * 4);
    int*   deg    = zerob;
    int*   bflagA = zerob + N;
    float* bnsumA = (float*)(zerob + N + 3 * 512);
    int*   misc   = zerob + N + 3 * 512 + 3 * 8 * 512;
    int*   done   = misc;
    int*   csrctr = misc + 1;

    const int Z = cdiv(nzero, 256);
    const int Wb = 3 * 40 * 256 * 8 / 256;   // 960
    const int prep_grid = Z + Wb + 128 + 128 + 24 + 48;

    prep_k<<<prep_grid, 256, 0, stream>>>(W_self, b_rule, W_in, W_h1, W_h2,
                                          centers, logsig, wsp, winp, wh1p, wh2p,
                                          pcB, pccc, zerob, nzero, Z, Wb);

    gemm_mn<0, 2><<<gx, 256, 0, stream>>>((const u16*)x, nullptr, nullptr, winp,
                                          nullptr, 0,
                                          b_in, nullptr, h16, nullptr,
                                          pcB, pccc, mu16, bflagA,
                                          nullptr, nullptr, nullptr, nullptr,
                                          nullptr, nullptr, nullptr, nullptr,
                                          nullptr, 0, N);

    for (int l = 0; l < 3; ++l) {
        int* bf = bflagA + l * 512;
        float* bns = bnsumA + (size_t)l * 8 * 512;
        gemm_mn<1, 69><<<gx, 256, 0, stream>>>(agg16, h16, mu16,
                                               wsp + (size_t)l * 40 * 256 * 8,
                                               W_rule, l,
                                               b_self + l * 256, bf, pre16, bns,
                                               nullptr, nullptr, nullptr, nullptr,
                                               e_src, e_dst, deg, indptr, cursor,
                                               deginv, ssrc, csrctr, done, E, N);
        if (l < 2) {
            upd_k<1><<<cdiv(N, 64), 256, 0, stream>>>(pre16, bns, gamma + l * 256,
                                                      beta + l * 256, h16,
                                                      pcB + (size_t)(l + 1) * 16 * 512,
                                                      pccc + (l + 1) * 16, mu16,
                                                      bflagA + (l + 1) * 512,
                                                      nullptr, nullptr, nullptr, nullptr,
                                                      nullptr, N);
        } else {
            upd_k<2><<<cdiv(N, 64), 256, 0, stream>>>(pre16, bns, gamma + l * 256,
                                                      beta + l * 256, h16,
                                                      nullptr, nullptr, nullptr, nullptr,
                                                      wh1p, b_h1, wh2p, b_h2,
                                                      (float*)d_out, N);
        }
    }
}

// Round 15
// 269.388 us; speedup vs baseline: 1.0582x; 1.0582x over previous
//
#include <hip/hip_runtime.h>
#include <hip/hip_fp16.h>
#include <cstdint>
#include <cstddef>

using u16 = unsigned short;
using u32 = unsigned int;

typedef _Float16 half8 __attribute__((ext_vector_type(8)));
typedef float f32x4 __attribute__((ext_vector_type(4)));

#define MF(a, b, c) __builtin_amdgcn_mfma_f32_16x16x32_f16((a), (b), (c), 0, 0, 0)

static inline int cdiv(int a, int b) { return (a + b - 1) / b; }

// ===========================================================================
// prep_k: fused zero-init + weight panelization + rule precompute. (r10)
// ===========================================================================

__global__ void prep_k(const float* __restrict__ Wr,
                       const float* __restrict__ Ws, const float* __restrict__ br,
                       const float* __restrict__ W_in, const float* __restrict__ W_h1,
                       const float* __restrict__ W_h2,
                       const float* __restrict__ centers, const float* __restrict__ logsig,
                       u16* __restrict__ wcat,
                       u16* __restrict__ winp, u16* __restrict__ wh1p,
                       u16* __restrict__ wh2p,
                       u16* __restrict__ pcB, float* __restrict__ pccc,
                       int* __restrict__ zerobase, int nzero,
                       int Z, int Wb) {
    const int bid = blockIdx.x;
    const int tid = threadIdx.x;
    if (bid < Z) {                                   // zero-init region
        int i = bid * 256 + tid;
        if (i < nzero) zerobase[i] = 0;
        return;
    }
    if (bid < Z + Wb) {                              // wcat panels [552][256][8] x3 layers
        size_t t = (size_t)(bid - Z) * 256 + tid;
        const size_t PL = 552u * 256u * 8u;
        int l = (int)(t / PL);
        size_t rem = t - (size_t)l * PL;
        int kp = (int)(rem >> 11);
        int o = (int)((rem >> 3) & 255);
        int e = (int)(rem & 7);
        int k = kp * 8 + e;
        float v;
        if (k < 4096)      v = Wr[((((size_t)l * 16 + (k >> 8)) * 256) + (k & 255)) * 256 + o];
        else if (k < 4352) v = Ws[(((size_t)l * 256) + (k - 4096)) * 256 + o];
        else if (k < 4368) v = br[(((size_t)l * 16) + (k - 4352)) * 256 + o];
        else               v = 0.f;
        union { u16 u; _Float16 h; } c; c.h = (_Float16)v;
        wcat[t] = c.u;
        return;
    }
    if (bid < Z + Wb + 128) {                        // panelize W_in (K=128,M=256)
        size_t t = (size_t)(bid - Z - Wb) * 256 + tid;
        int e = (int)(t & 7), o = (int)((t >> 3) & 255);
        int kp = (int)(t >> 11);
        union { u16 u; _Float16 h; } c; c.h = (_Float16)W_in[(size_t)(kp * 8 + e) * 256 + o];
        winp[t] = c.u;
        return;
    }
    if (bid < Z + Wb + 256) {                        // panelize W_h1 (K=256,M=128)
        size_t t = (size_t)(bid - Z - Wb - 128) * 256 + tid;
        int e = (int)(t & 7), o = (int)((t >> 3) & 127);
        int kp = (int)(t >> 10);
        union { u16 u; _Float16 h; } c; c.h = (_Float16)W_h1[(size_t)(kp * 8 + e) * 128 + o];
        wh1p[t] = c.u;
        return;
    }
    if (bid < Z + Wb + 256 + 24) {                   // panelize W_h2 (K=128,M=40->48 pad)
        int t = (bid - Z - Wb - 256) * 256 + tid;    // 16*48*8 = 6144
        int e = t & 7, col = (t >> 3) % 48, p = t / 384;
        int k = p * 8 + e;
        float v = (col < 40) ? W_h2[(size_t)k * 40 + col] : 0.f;
        union { u16 u; _Float16 h; } c; c.h = (_Float16)v;
        wh2p[t] = c.u;
        return;
    }
    {                                                // pc_build: 48 blocks (l*16+r)
        int lr = bid - (Z + Wb + 256 + 24);
        size_t idx = (size_t)lr * 256 + tid;
        float ls = logsig[idx];
        float inv = expf(-2.f * ls);
        float c = centers[idx];
        union { u16 u; _Float16 h; } c1, c2;
        c1.h = (_Float16)inv;
        c2.h = (_Float16)(-2.f * c * inv);
        pcB[(size_t)lr * 512 + tid] = c1.u;          // B[k][r] = inv_s2[r][k], k<256
        pcB[(size_t)lr * 512 + 256 + tid] = c2.u;    // B[256+k][r] = -2 c inv
        __shared__ float sm[256];
        sm[tid] = c * c * inv;
        __syncthreads();
        for (int s = 128; s > 0; s >>= 1) { if (tid < s) sm[tid] += sm[tid + s]; __syncthreads(); }
        if (tid == 0) pccc[lr] = sm[0];
    }
}

// ===========================================================================
// gemm_mn: full-width 128x256 LDS-staged GEMM (r10-verified, 289us best).
// One change vs r10: BN atomics spread over 8 shadow copies of bnsum
// (blockIdx.x & 7) — r6/r8/r10/r11 all show gemm<1> pinned at 52-64us across
// wildly different staging schemes; the invariant cost is 391 contenders per
// BN address (200K device-scope float RMWs on 32 cache lines). 8 shadows =
// 49 contenders/address. Per-block partials identical; only inter-block
// addition grouping changes (within BN noise, threshold 4.6e-3 vs 9.8e-4).
// MODE 0: h16 = relu(x@winp+b_in); fused membership from the LDS out-tile.
// MODE 1: cold-gated CSR prologue; pre16 = [mu*agg|h|mu]@Wcat + b_self.
// ===========================================================================

template <int MODE, int NCHUNK>
__launch_bounds__(256, 2)
__global__ void gemm_mn(const u16* __restrict__ A, const u16* __restrict__ A2,
                        const u16* __restrict__ MU, const u16* __restrict__ Bp,
                        const float* __restrict__ bias, const int* __restrict__ bflag,
                        u16* __restrict__ outH, float* __restrict__ bnsum,
                        const u16* __restrict__ pcB, const float* __restrict__ pccc,
                        u16* __restrict__ mu16, int* __restrict__ bflagN,
                        const int* __restrict__ esrc, const int* __restrict__ edst,
                        int* __restrict__ deg, int* __restrict__ indptr,
                        int* __restrict__ cursor, float* __restrict__ deginv,
                        int* __restrict__ ssrc, int* __restrict__ csrctr,
                        int* __restrict__ done, int E, int nrows) {
    __shared__ __align__(16) u16 lds[24576];   // lA 8192 | lB 16384; out tile reuses [0..17407]
    __shared__ float bnbuf[2048];              // [wave][256 cols][s,ss]
    __shared__ int ssm[256];                   // cold-path scan
    u16* lA = lds;
    u16* lB = lds + 8192;
    const int tid = threadIdx.x;
    const int row0 = blockIdx.x * 128;
    const int lane = tid & 63;
    const int q = lane >> 4, mm = lane & 15;
    const int wave = tid >> 6;
    int nr = nrows - row0; if (nr > 128) nr = 128;

    // ---- cold-gated CSR build + own-row aggregation (MODE 1 only; r10-verified) ----
    if (MODE == 1 && bflag[511] != 0) {
        int bseq = 0;
        auto gbar = [&]() {
            __threadfence();
            __syncthreads();
            ++bseq;
            if (tid == 0) {
                atomicAdd(csrctr, 1);
                while (atomicAdd(csrctr, 0) < (int)gridDim.x * bseq)
                    __builtin_amdgcn_s_sleep(2);
            }
            __syncthreads();
        };
        if (*done == 0) {
            for (int e = blockIdx.x * 256 + tid; e < E; e += (int)gridDim.x * 256)
                atomicAdd(&deg[edst[e]], 1);
            gbar();
            if (blockIdx.x == 0) {                   // 256-thread scan
                const int n = nrows;
                const int chunk = (n + 255) >> 8;
                int s0 = tid * chunk, s1 = s0 + chunk;
                if (s1 > n) s1 = n; if (s0 > n) s0 = n;
                int tot = 0;
                for (int i = s0; i < s1; ++i) tot += atomicAdd(&deg[i], 0);
                ssm[tid] = tot; __syncthreads();
                for (int off = 1; off < 256; off <<= 1) {
                    int t = (tid >= off) ? ssm[tid - off] : 0;
                    __syncthreads(); ssm[tid] += t; __syncthreads();
                }
                int base = ssm[tid] - tot;
                for (int i = s0; i < s1; ++i) {
                    int d = atomicAdd(&deg[i], 0);
                    indptr[i] = base; cursor[i] = base;
                    deginv[i] = 1.f / (float)(d > 1 ? d : 1);
                    base += d;
                }
                if (tid == 255) indptr[nrows] = ssm[255];
            }
            gbar();
            for (int e = blockIdx.x * 256 + tid; e < E; e += (int)gridDim.x * 256) {
                int d = edst[e];
                int pos = atomicAdd(&cursor[d], 1);
                ssrc[pos] = esrc[e];
            }
            gbar();
            if (blockIdx.x == 0 && tid == 0) *done = 1;
        }
        if (bflag[blockIdx.x] != 0) {                // aggregate OWN 128 rows
            for (int node = row0 + wave; node < row0 + 128 && node < nrows; node += 4) {
                int j0 = indptr[node], j1 = indptr[node + 1];
                float a0 = 0, a1 = 0, a2 = 0, a3 = 0;
                for (int j = j0; j < j1; ++j) {
                    int sN = ssrc[j];
                    union { uint2 u; _Float16 h[4]; } hv;
                    hv.u = *(const uint2*)(A2 + (size_t)sN * 256 + lane * 4);
                    a0 += (float)hv.h[0]; a1 += (float)hv.h[1];
                    a2 += (float)hv.h[2]; a3 += (float)hv.h[3];
                }
                float di = deginv[node];
                union { uint2 u; _Float16 h[4]; } o;
                o.h[0] = (_Float16)(a0 * di); o.h[1] = (_Float16)(a1 * di);
                o.h[2] = (_Float16)(a2 * di); o.h[3] = (_Float16)(a3 * di);
                *(uint2*)((u16*)A + (size_t)node * 256 + lane * 4) = o.u;
            }
        }
        __threadfence_block();
        __syncthreads();
    }

    f32x4 acc[2][16];
#pragma unroll
    for (int i = 0; i < 2; ++i)
#pragma unroll
        for (int j = 0; j < 16; ++j) acc[i][j] = (f32x4){0.f, 0.f, 0.f, 0.f};

    int cb = 0, cbEnd = NCHUNK;
    if (MODE == 1 && bflag[blockIdx.x] == 0) { cb = 64; cbEnd = 68; }  // mu==0: fuzzy+mu K exact-zero

    for (; cb < cbEnd; ++cb) {
        // B chunk: 8 k-panels x 256 cols  (2048 uint4)
#pragma unroll
        for (int it = 0; it < 8; ++it) {
            int idx = it * 256 + tid;
            int p = idx >> 8, col = idx & 255;
            uint4 v = *(const uint4*)(Bp + (((size_t)(cb * 8 + p)) * 256 + col) * 8);
            *(uint4*)(lB + (size_t)idx * 8) = v;
        }
        // A chunk: 128 rows x 64 k  (1024 uint4)
#pragma unroll
        for (int it = 0; it < 4; ++it) {
            int idx = it * 256 + tid;
            int p = idx >> 7, row = idx & 127;
            int grow = row0 + row; if (grow >= nrows) grow = nrows - 1;
            uint4 v;
            if (MODE == 0) {
                const float* xr = (const float*)A + (size_t)grow * 128 + cb * 64 + (p << 3);
                float4 f0 = *(const float4*)xr;
                float4 f1 = *(const float4*)(xr + 4);
                union { uint4 u4; _Float16 h[8]; } cv;
                cv.h[0] = (_Float16)f0.x; cv.h[1] = (_Float16)f0.y;
                cv.h[2] = (_Float16)f0.z; cv.h[3] = (_Float16)f0.w;
                cv.h[4] = (_Float16)f1.x; cv.h[5] = (_Float16)f1.y;
                cv.h[6] = (_Float16)f1.z; cv.h[7] = (_Float16)f1.w;
                v = cv.u4;
            } else {
                if (cb < 64) {
                    int r = cb >> 2;
                    int i0 = ((cb & 3) << 6) + (p << 3);
                    v = *(const uint4*)(A + (size_t)grow * 256 + i0);
                    union { u16 u; _Float16 h; } mu; mu.u = MU[(size_t)grow * 16 + r];
                    union { uint4 u4; _Float16 h[8]; } wv; wv.u4 = v;
#pragma unroll
                    for (int j = 0; j < 8; ++j) wv.h[j] = wv.h[j] * mu.h;
                    v = wv.u4;
                } else if (cb < 68) {
                    int i0 = ((cb - 64) << 6) + (p << 3);
                    v = *(const uint4*)(A2 + (size_t)grow * 256 + i0);
                } else {
                    int j0 = p << 3;
                    if (j0 < 16) v = *(const uint4*)(MU + (size_t)grow * 16 + j0);
                    else v = (uint4){0, 0, 0, 0};
                }
            }
            *(uint4*)(lA + (size_t)idx * 8) = v;
        }
        __syncthreads();
#pragma unroll
        for (int kc = 0; kc < 2; ++kc) {
            int pp = kc * 4 + q;
            half8 af0 = *(const half8*)(lA + ((size_t)pp * 128 + wave * 32 + mm) * 8);
            half8 af1 = *(const half8*)(lA + ((size_t)pp * 128 + wave * 32 + 16 + mm) * 8);
#pragma unroll
            for (int nt = 0; nt < 16; ++nt) {
                half8 bf = *(const half8*)(lB + ((size_t)pp * 256 + nt * 16 + mm) * 8);
                acc[0][nt] = MF(af0, bf, acc[0][nt]);
                acc[1][nt] = MF(af1, bf, acc[1][nt]);
            }
        }
        __syncthreads();
    }

    // ---- BN column sums (MODE 1): 8-way shadow atomics (contention spread) ----
    if (MODE == 1) {
#pragma unroll
        for (int nt = 0; nt < 16; ++nt) {
            int cl = nt * 16 + mm;
            float bb = bias[cl];
            float s = 0.f, ss = 0.f;
#pragma unroll
            for (int mt = 0; mt < 2; ++mt) {
#pragma unroll
                for (int r = 0; r < 4; ++r) {
                    int row = wave * 32 + mt * 16 + q * 4 + r;
                    float v = acc[mt][nt][r] + bb;
                    if (row < nr) { s += v; ss += v * v; }
                }
            }
            s += __shfl_xor(s, 16);  s += __shfl_xor(s, 32);
            ss += __shfl_xor(ss, 16); ss += __shfl_xor(ss, 32);
            if (q == 0) {
                bnbuf[(wave * 256 + cl) * 2 + 0] = s;
                bnbuf[(wave * 256 + cl) * 2 + 1] = ss;
            }
        }
        __syncthreads();
        {
            float s  = bnbuf[tid * 2]     + bnbuf[(256 + tid) * 2]
                     + bnbuf[(512 + tid) * 2] + bnbuf[(768 + tid) * 2];
            float ss = bnbuf[tid * 2 + 1] + bnbuf[(256 + tid) * 2 + 1]
                     + bnbuf[(512 + tid) * 2 + 1] + bnbuf[(768 + tid) * 2 + 1];
            float* bnl = bnsum + (blockIdx.x & 7) * 512;   // 8 shadow copies
            atomicAdd(&bnl[tid], s);
            atomicAdd(&bnl[256 + tid], ss);
        }
    }

    // ---- store halves through LDS; MODE 0 fuses membership from the tile ----
    f32x4 macc0 = (f32x4){0.f, 0.f, 0.f, 0.f};
    f32x4 macc1 = (f32x4){0.f, 0.f, 0.f, 0.f};
#pragma unroll
    for (int h = 0; h < 2; ++h) {
        __syncthreads();
#pragma unroll
        for (int nt = 0; nt < 8; ++nt) {
            int cl = h * 128 + nt * 16 + mm;
            float bb = bias[cl];
#pragma unroll
            for (int mt = 0; mt < 2; ++mt) {
#pragma unroll
                for (int r = 0; r < 4; ++r) {
                    int row = wave * 32 + mt * 16 + q * 4 + r;
                    float v = acc[mt][h * 8 + nt][r] + bb;
                    if (MODE == 0) v = fmaxf(v, 0.f);
                    union { u16 u; _Float16 hh; } cc; cc.hh = (_Float16)v;
                    lds[row * 136 + nt * 16 + mm] = cc.u;
                }
            }
        }
        __syncthreads();
#pragma unroll
        for (int it = 0; it < 8; ++it) {
            int idx = it * 256 + tid;
            int row = idx >> 4, cp = idx & 15;
            if (row < nr) {
                uint4 v = *(const uint4*)(lds + row * 136 + cp * 8);
                *(uint4*)(outH + (size_t)(row0 + row) * 256 + h * 128 + cp * 8) = v;
            }
        }
        if (MODE == 0) {
            // membership partial MFMA over this half's 128 h-dims (reads tile)
            const u16* brow = pcB + (size_t)mm * 512;
#pragma unroll
            for (int it2 = 0; it2 < 4; ++it2) {
                int lk = it2 * 32 + q * 8;
                half8 b1 = *(const half8*)(brow + h * 128 + lk);
                half8 b2 = *(const half8*)(brow + 256 + h * 128 + lk);
                half8 a0 = *(const half8*)(lds + ((size_t)(wave * 32 + mm)) * 136 + lk);
                half8 a1 = *(const half8*)(lds + ((size_t)(wave * 32 + 16 + mm)) * 136 + lk);
                macc0 = MF(a0 * a0, b1, macc0);
                macc0 = MF(a0, b2, macc0);
                macc1 = MF(a1 * a1, b1, macc1);
                macc1 = MF(a1, b2, macc1);
            }
        }
    }

    if (MODE == 0) {
        float cc = pccc[mm];
        bool any = false;
#pragma unroll
        for (int g = 0; g < 2; ++g) {
            f32x4 macc = g ? macc1 : macc0;
#pragma unroll
            for (int r = 0; r < 4; ++r) {
                float d = macc[r] + cc;
                float f = expf(-0.5f * d);
                float s = f;
                s += __shfl_xor(s, 1); s += __shfl_xor(s, 2);
                s += __shfl_xor(s, 4); s += __shfl_xor(s, 8);
                int node = row0 + (wave * 2 + g) * 16 + q * 4 + r;
                if (node < nrows) {
                    union { u16 u; _Float16 hh; } c2;
                    c2.hh = (_Float16)(f / (s + 1e-12f));
                    mu16[(size_t)node * 16 + mm] = c2.u;
                    if (c2.u != 0) any = true;       // f16-visible firing only
                }
            }
        }
        if (__any(any) && lane == 0) {
            atomicOr(&bflagN[blockIdx.x], 1);
            atomicOr(&bflagN[511], 1);
        }
    }
}

// ===========================================================================
// upd_k: BN alpha/shift from 8-shadow bnsum (summed in-block), residual
// update. (r10 otherwise)
// TAIL 1: write h16 + next-layer membership (mu16, flags).
// TAIL 2: head fused from registers (v16 IS the MFMA A-fragment layout).
// ===========================================================================

template <int TAIL>
__launch_bounds__(256)
__global__ void upd_k(const u16* __restrict__ pre16, const float* __restrict__ bnsum,
                      const float* __restrict__ gamma, const float* __restrict__ beta,
                      u16* __restrict__ h16,
                      const u16* __restrict__ pcB, const float* __restrict__ pccc,
                      u16* __restrict__ mu16, int* __restrict__ bflag,
                      const u16* __restrict__ wh1p, const float* __restrict__ bh1,
                      const u16* __restrict__ wh2p, const float* __restrict__ bh2,
                      float* __restrict__ outF, int n) {
    const int tid = threadIdx.x;
    __shared__ float l_ab[512];
    __shared__ __align__(16) u16 qt[4][2176];        // TAIL2: per-wave [16][136]
    {
        float su = 0.f, sq = 0.f;
#pragma unroll
        for (int c = 0; c < 8; ++c) {                // sum the 8 shadow copies
            su += bnsum[c * 512 + tid];
            sq += bnsum[c * 512 + 256 + tid];
        }
        float invn = 1.f / (float)n;
        float m = su * invn;
        float al = gamma[tid] * rsqrtf(sq * invn - m * m + 1e-5f);
        l_ab[tid] = al;
        l_ab[256 + tid] = beta[tid] - m * al;
    }
    __syncthreads();

    const int lane = tid & 63, wave = tid >> 6;
    const int q = lane >> 4, mm = lane & 15;
    const int n0 = (blockIdx.x * 4 + wave) * 16;
    if (n0 >= n) return;
    const int node = n0 + mm;
    const bool valid = node < n;
    const int nodeC = valid ? node : n - 1;
    const size_t base = (size_t)nodeC * 256 + q * 8;

    half8 v16[8];
#pragma unroll
    for (int b = 0; b < 8; ++b) {
        int c = b * 32 + q * 8;
        float4 alA = *(const float4*)(l_ab + c);
        float4 alB = *(const float4*)(l_ab + c + 4);
        float4 shA = *(const float4*)(l_ab + 256 + c);
        float4 shB = *(const float4*)(l_ab + 256 + c + 4);
        float aarr[8] = {alA.x, alA.y, alA.z, alA.w, alB.x, alB.y, alB.z, alB.w};
        float harr[8] = {shA.x, shA.y, shA.z, shA.w, shB.x, shB.y, shB.z, shB.w};
        union { uint4 u; _Float16 hh[8]; } p, hv, o;
        p.u  = *(const uint4*)(pre16 + base + b * 32);
        hv.u = *(const uint4*)(h16 + base + b * 32);
#pragma unroll
        for (int j = 0; j < 8; ++j) {
            float v = (float)hv.hh[j] + fmaxf((float)p.hh[j] * aarr[j] + harr[j], 0.f);
            o.hh[j] = (_Float16)v;
        }
        if (TAIL == 1 && valid) *(uint4*)(h16 + base + b * 32) = o.u;
        v16[b] = *(half8*)&o;
    }

    if (TAIL == 1) {
        const u16* brow = pcB + (size_t)mm * 512;
        f32x4 acc = (f32x4){0.f, 0.f, 0.f, 0.f};
#pragma unroll
        for (int it = 0; it < 16; ++it) {
            half8 a = v16[it & 7];
            if (it < 8) a = a * a;
            half8 bb = *(const half8*)(brow + it * 32 + q * 8);
            acc = MF(a, bb, acc);
        }
        float cc = pccc[mm];
        bool any = false;
#pragma unroll
        for (int r = 0; r < 4; ++r) {
            float d = acc[r] + cc;
            float f = expf(-0.5f * d);
            float s = f;
            s += __shfl_xor(s, 1); s += __shfl_xor(s, 2);
            s += __shfl_xor(s, 4); s += __shfl_xor(s, 8);
            int nd = n0 + q * 4 + r;
            if (nd < n) {
                union { u16 u; _Float16 h; } c2;
                c2.h = (_Float16)(f / (s + 1e-12f));
                mu16[(size_t)nd * 16 + mm] = c2.u;
                if (c2.u != 0) any = true;           // f16-visible firing only
            }
        }
        if (__any(any) && lane == 0) {
            atomicOr(&bflag[n0 >> 7], 1);
            atomicOr(&bflag[511], 1);
        }
    }

    if (TAIL == 2) {
        u16* qw = qt[wave];
        f32x4 hq[8];
#pragma unroll
        for (int j = 0; j < 8; ++j) hq[j] = (f32x4){0.f, 0.f, 0.f, 0.f};
#pragma unroll
        for (int b = 0; b < 8; ++b) {
            half8 a = v16[b];
            const u16* bp = wh1p + ((size_t)((b * 4 + q) * 128) + mm) * 8;
#pragma unroll
            for (int nt = 0; nt < 8; ++nt) {
                half8 bf = *(const half8*)(bp + nt * 128);
                hq[nt] = MF(a, bf, hq[nt]);
            }
        }
#pragma unroll
        for (int nt = 0; nt < 8; ++nt) {
            int cl = nt * 16 + mm;
            float bb = bh1[cl];
#pragma unroll
            for (int r = 0; r < 4; ++r) {
                float v = fmaxf(hq[nt][r] + bb, 0.f);
                union { u16 u; _Float16 h; } cc; cc.h = (_Float16)v;
                qw[(q * 4 + r) * 136 + cl] = cc.u;
            }
        }
        const bool c2ok = (mm < 8);
        float b0 = bh2[mm], b1 = bh2[16 + mm];
        float b2 = c2ok ? bh2[32 + mm] : 0.f;
        f32x4 hacc[3];
#pragma unroll
        for (int t = 0; t < 3; ++t) hacc[t] = (f32x4){0.f, 0.f, 0.f, 0.f};
#pragma unroll
        for (int c = 0; c < 4; ++c) {
            half8 a = *(const half8*)(qw + (size_t)mm * 136 + c * 32 + q * 8);
#pragma unroll
            for (int t = 0; t < 3; ++t) {
                half8 b = *(const half8*)(wh2p + ((size_t)(c * 4 + q) * 48 + t * 16 + mm) * 8);
                hacc[t] = MF(a, b, hacc[t]);
            }
        }
#pragma unroll
        for (int r = 0; r < 4; ++r) {
            int nd = n0 + q * 4 + r;
            float v0 = hacc[0][r] + b0;
            float v1 = hacc[1][r] + b1;
            float v2 = c2ok ? (hacc[2][r] + b2) : -3e38f;
            float m = fmaxf(fmaxf(v0, v1), v2);
            m = fmaxf(m, __shfl_xor(m, 1)); m = fmaxf(m, __shfl_xor(m, 2));
            m = fmaxf(m, __shfl_xor(m, 4)); m = fmaxf(m, __shfl_xor(m, 8));
            float e0 = expf(v0 - m), e1 = expf(v1 - m);
            float e2 = c2ok ? expf(v2 - m) : 0.f;
            float s = e0 + e1 + e2;
            s += __shfl_xor(s, 1); s += __shfl_xor(s, 2);
            s += __shfl_xor(s, 4); s += __shfl_xor(s, 8);
            float is = 1.f / s;
            if (nd < n) {
                float* op = outF + (size_t)nd * 40;
                op[mm] = e0 * is;
                op[16 + mm] = e1 * is;
                if (c2ok) op[32 + mm] = e2 * is;
            }
        }
    }
}

// ===========================================================================
// Launch: 8 dispatches (prep, g0, 3x(g1, upd)).
// ===========================================================================

extern "C" void kernel_launch(void* const* d_in, const int* in_sizes, int n_in,
                              void* d_out, int out_size, void* d_ws, size_t ws_size,
                              hipStream_t stream) {
    const float* x       = (const float*)d_in[0];
    const int*   ei      = (const int*)d_in[1];
    const float* W_in    = (const float*)d_in[2];
    const float* b_in    = (const float*)d_in[3];
    const float* centers = (const float*)d_in[4];
    const float* logsig  = (const float*)d_in[5];
    const float* W_rule  = (const float*)d_in[6];
    const float* b_rule  = (const float*)d_in[7];
    const float* W_self  = (const float*)d_in[8];
    const float* b_self  = (const float*)d_in[9];
    const float* gamma   = (const float*)d_in[10];
    const float* beta    = (const float*)d_in[11];
    const float* W_h1    = (const float*)d_in[12];
    const float* b_h1    = (const float*)d_in[13];
    const float* W_h2    = (const float*)d_in[14];
    const float* b_h2    = (const float*)d_in[15];

    const int N = in_sizes[0] / 128;
    const int E = in_sizes[1] / 2;
    const int* e_src = ei;
    const int* e_dst = ei + E;

    char* w = (char*)d_ws;
    size_t off = 0;
    auto alloc = [&](size_t bytes) -> void* {
        void* p = w + off;
        off = (off + bytes + 255) & ~(size_t)255;
        return p;
    };

    const int gx = cdiv(N, 128);

    u16*   h16    = (u16*)  alloc((size_t)N * 256 * 2);
    u16*   pre16  = (u16*)  alloc((size_t)N * 256 * 2);
    u16*   agg16  = (u16*)  alloc((size_t)N * 256 * 2);
    u16*   mu16   = (u16*)  alloc((size_t)N * 16 * 2);
    u16*   wcat   = (u16*)  alloc((size_t)3 * 552 * 256 * 8 * 2);
    u16*   winp   = (u16*)  alloc((size_t)16 * 256 * 8 * 2);
    u16*   wh1p   = (u16*)  alloc((size_t)32 * 128 * 8 * 2);
    u16*   wh2p   = (u16*)  alloc((size_t)16 * 48 * 8 * 2);
    u16*   pcB    = (u16*)  alloc((size_t)48 * 512 * 2);
    float* pccc   = (float*)alloc((size_t)48 * 4);
    int*   indptr = (int*)  alloc((size_t)(N + 1) * 4);
    int*   cursor = (int*)  alloc((size_t)N * 4);
    float* deginv = (float*)alloc((size_t)N * 4);
    int*   ssrc   = (int*)  alloc((size_t)E * 4);
    // zero region: [deg N][bflag 3*512][bnsum8 3*8*512][done, csrctr, pad]
    const int nzero = N + 3 * 512 + 3 * 8 * 512 + 16;
    int*   zerob  = (int*)  alloc((size_t)nzero * 4);
    int*   deg    = zerob;
    int*   bflagA = zerob + N;
    float* bnsumA = (float*)(zerob + N + 3 * 512);
    int*   misc   = zerob + N + 3 * 512 + 3 * 8 * 512;
    int*   done   = misc;
    int*   csrctr = misc + 1;

    const int Z = cdiv(nzero, 256);
    const int Wb = 3 * 552 * 256 * 8 / 256;   // 13248
    const int prep_grid = Z + Wb + 128 + 128 + 24 + 48;

    prep_k<<<prep_grid, 256, 0, stream>>>(W_rule, W_self, b_rule, W_in, W_h1, W_h2,
                                          centers, logsig, wcat, winp, wh1p, wh2p,
                                          pcB, pccc, zerob, nzero, Z, Wb);

    gemm_mn<0, 2><<<gx, 256, 0, stream>>>((const u16*)x, nullptr, nullptr, winp,
                                          b_in, nullptr, h16, nullptr,
                                          pcB, pccc, mu16, bflagA,
                                          nullptr, nullptr, nullptr, nullptr,
                                          nullptr, nullptr, nullptr, nullptr,
                                          nullptr, 0, N);

    for (int l = 0; l < 3; ++l) {
        int* bf = bflagA + l * 512;
        float* bns = bnsumA + (size_t)l * 8 * 512;
        gemm_mn<1, 69><<<gx, 256, 0, stream>>>(agg16, h16, mu16,
                                               wcat + (size_t)l * 552 * 256 * 8,
                                               b_self + l * 256, bf, pre16, bns,
                                               nullptr, nullptr, nullptr, nullptr,
                                               e_src, e_dst, deg, indptr, cursor,
                                               deginv, ssrc, csrctr, done, E, N);
        if (l < 2) {
            upd_k<1><<<cdiv(N, 64), 256, 0, stream>>>(pre16, bns, gamma + l * 256,
                                                      beta + l * 256, h16,
                                                      pcB + (size_t)(l + 1) * 16 * 512,
                                                      pccc + (l + 1) * 16, mu16,
                                                      bflagA + (l + 1) * 512,
                                                      nullptr, nullptr, nullptr, nullptr,
                                                      nullptr, N);
        } else {
            upd_k<2><<<cdiv(N, 64), 256, 0, stream>>>(pre16, bns, gamma + l * 256,
                                                      beta + l * 256, h16,
                                                      nullptr, nullptr, nullptr, nullptr,
                                                      wh1p, b_h1, wh2p, b_h2,
                                                      (float*)d_out, N);
        }
    }
}